// Round 1
// 218.401 us; speedup vs baseline: 1.0330x; 1.0330x over previous
//
#include <hip/hip_runtime.h>
#include <hip/hip_bf16.h>
#include <math.h>

// Problem: B=4, C=256, H=W=64 (N=4096), IC=128. I/O float32.
// R9: flash rewritten — swapped QK^T (mfma(K,Q) -> P^T in-register, lane owns a
//     q-row), cvt_pk_bf16 + ds_bpermute quad-exchange builds PV A-frags with NO
//     Ps LDS buffer (LDS 100KB->64KB). Blocks shrunk to 4 waves / q-tile 128,
//     grid 512 = 2 independent barrier domains per CU (anti-phase overlap).
//     l via per-lane f32 sum + 2 shfl_xor (ones-MFMA dropped).
typedef unsigned short ushort_t;
typedef __attribute__((ext_vector_type(8))) short     short8;   // bf16x8 MFMA frag
typedef __attribute__((ext_vector_type(8))) _Float16  half8;    // f16x8 MFMA frag
typedef __attribute__((ext_vector_type(8))) unsigned short ushort8;
typedef __attribute__((ext_vector_type(4))) float     float4v;

__device__ __forceinline__ float b2f(ushort_t u) {
    return __uint_as_float(((unsigned)u) << 16);
}
__device__ __forceinline__ ushort_t f2b(float f) {
    unsigned i = __float_as_uint(f);
    return (ushort_t)((i + 0x7FFFu + ((i >> 16) & 1u)) >> 16);  // RNE
}
__device__ __forceinline__ void split2(float v, ushort_t& h, ushort_t& l) {
    h = f2b(v);
    l = f2b(v - b2f(h));   // combined rel err ~2^-17
}
__device__ __forceinline__ void glds16(const ushort_t* g, ushort_t* l) {
    __builtin_amdgcn_global_load_lds((const __attribute__((address_space(1))) void*)g,
                                     (__attribute__((address_space(3))) void*)l, 16, 0, 0);
}
__device__ __forceinline__ unsigned int pack2bf(float lo, float hi) {
    unsigned int r;
    asm("v_cvt_pk_bf16_f32 %0, %1, %2" : "=v"(r) : "v"(lo), "v"(hi));
    return r;
}

// ---- workspace layout (bytes) ----
#define WTFH_OFF   0            // 192 KB proj weights B-frag hi
#define WTFL_OFF   196608       // 192 KB lo
#define WWBH_OFF   393216       // 64 KB w_w bf16 hi
#define WWBL_OFF   458752       // 64 KB lo
#define BIAS_OFF   524288       // 384 f32
#define STATS_OFF  526336       // 512 f32
#define PROJF_OFF  1048576      // 8 MB fp16 (theta|phi) [b][n][256]
#define GT_OFF     9437184      // 4 MB bf16 g transposed [b][ic][n]
#define OPART_OFF  13631488     // KQ*8 MB f32 partial O; oml after
#define WY_OFF     1048576      // wy bf16 reuses PROJF region (dead after flash)

__global__ void prep_k(const float* __restrict__ dx_w, const float* __restrict__ dy_w,
                       const float* __restrict__ g_w,  const float* __restrict__ dx_b,
                       const float* __restrict__ dy_b, const float* __restrict__ g_b,
                       const float* __restrict__ w_w,
                       ushort_t* __restrict__ wtfh, ushort_t* __restrict__ wtfl,
                       ushort_t* __restrict__ wwbh, ushort_t* __restrict__ wwbl,
                       float* __restrict__ bias) {
    int idx = blockIdx.x * 256 + threadIdx.x;          // 0..98303
    int j = idx & 7, lane = (idx >> 3) & 63, kk = (idx >> 9) & 7, ot = idx >> 12;
    int o = ot * 16 + (lane & 15);
    int c = kk * 32 + ((lane >> 4) * 8) + j;
    float v;
    if (o < 128)      v = dx_w[o * 256 + c];
    else if (o < 256) v = dy_w[(o - 128) * 256 + c];
    else              v = g_w[(o - 256) * 256 + c];
    ushort_t h, l;
    split2(v, h, l);
    wtfh[idx] = h; wtfl[idx] = l;
    if (idx < 32768) {                                 // w_w [256][128]
        split2(w_w[idx], h, l);
        wwbh[idx] = h; wwbl[idx] = l;
    }
    if (idx < 384) {
        bias[idx] = (idx < 128) ? dx_b[idx]
                  : (idx < 256) ? dy_b[idx - 128]
                                : g_b[idx - 256];
    }
}

// ============================================================================
// Kernel 2: projections, 32-row n-tiles (512 blocks). Split-bf16 compute;
// theta/phi stored fp16 single (feeds fp16 S-phase), g stored bf16 into gT.
// ============================================================================
__global__ __launch_bounds__(256) void proj_k(const float* __restrict__ x,
                                              const float* __restrict__ y,
                                              const ushort_t* __restrict__ wtfh,
                                              const ushort_t* __restrict__ wtfl,
                                              const float* __restrict__ bias,
                                              ushort_t* __restrict__ projf,
                                              ushort_t* __restrict__ gT) {
    __shared__ ushort_t xT[2][32 * 256];   // [hi/lo][n][c], 32KB
    int b = blockIdx.y, n0 = blockIdx.x * 32;
    int tid = threadIdx.x;
    int w = tid >> 6, lane = tid & 63;
    int mrow = lane & 15, quad = lane >> 4, koff = quad * 8;
    int half = w & 1, sect = w >> 1;
    int arow = half * 16 + mrow;

    for (int s = 0; s < 2; s++) {
        if (s) __syncthreads();
        const float* src = s ? y : x;
        #pragma unroll
        for (int i = 0; i < 4; i++) {
            int ch = tid + i * 256;
            int c = ch >> 2, off = (ch & 3) * 8;
            const float* p = src + (size_t)(b * 256 + c) * 4096 + n0 + off;
            float4v v0 = *(const float4v*)p;
            float4v v1 = *(const float4v*)(p + 4);
            #pragma unroll
            for (int jj = 0; jj < 4; jj++) {
                ushort_t h, l;
                split2(v0[jj], h, l);
                xT[0][(off + jj) * 256 + c] = h;
                xT[1][(off + jj) * 256 + c] = l;
                split2(v1[jj], h, l);
                xT[0][(off + 4 + jj) * 256 + c] = h;
                xT[1][(off + 4 + jj) * 256 + c] = l;
            }
        }
        __syncthreads();

        short8 fh[8], fl[8];
        #pragma unroll
        for (int kk = 0; kk < 8; kk++) {
            fh[kk] = *(const short8*)&xT[0][arow * 256 + kk * 32 + koff];
            fl[kk] = *(const short8*)&xT[1][arow * 256 + kk * 32 + koff];
        }

        int ot0 = s ? (8 + sect * 8) : (sect * 4);
        int ot1 = s ? (ot0 + 8) : (ot0 + 4);
        for (int ot = ot0; ot < ot1; ot++) {
            float4v acc = {0.f, 0.f, 0.f, 0.f};
            #pragma unroll
            for (int kk = 0; kk < 8; kk++) {
                short8 bh = *(const short8*)(wtfh + (size_t)((ot * 8 + kk) * 64 + lane) * 8);
                short8 bl = *(const short8*)(wtfl + (size_t)((ot * 8 + kk) * 64 + lane) * 8);
                acc = __builtin_amdgcn_mfma_f32_16x16x32_bf16(fh[kk], bh, acc, 0, 0, 0);
                acc = __builtin_amdgcn_mfma_f32_16x16x32_bf16(fh[kk], bl, acc, 0, 0, 0);
                acc = __builtin_amdgcn_mfma_f32_16x16x32_bf16(fl[kk], bh, acc, 0, 0, 0);
            }
            int o = ot * 16 + mrow;                  // C/D: col = lane&15
            float bo = bias[o];
            #pragma unroll
            for (int r = 0; r < 4; r++) {
                int n = n0 + half * 16 + quad * 4 + r;  // C/D: row = quad*4 + reg
                float v = acc[r] + bo;
                if (ot < 16) {
                    _Float16 hf = (_Float16)v;
                    projf[(size_t)(b * 4096 + n) * 256 + o] = *(ushort_t*)&hf;
                } else {
                    gT[(size_t)(b * 128 + (o - 256)) * 4096 + n] = f2b(v);
                }
            }
        }
    }
}

// ============================================================================
// Kernel 3: flash, 256 threads (4 waves x 32 q-rows = q-tile 128), K-split.
// Swapped S-phase: mfma(A=K, B=Q) -> accumulator holds P^T, i.e. each lane owns
// 16 P values of ONE q-row (q = lane&15, keys = ct*16 + quad*4 + r). Softmax is
// fully in-register: p = exp2(S*log2e - 64*log2e); l accumulated as per-lane
// f32 sum (cross-quad shfl reduce in epilogue). P -> PV A-frag rearrangement:
// v_cvt_pk_bf16_f32 pairs + 8 ds_bpermute + 4 cndmask per (strip,k2)
//   key 32*k2+8t+2u+{0,1} == pk[2k2+(t>>1)][u&1] @ lane (2(t&1)+(u>>1))*16+mrow.
// No Ps buffer -> LDS 64KB -> 2 blocks/CU (two independent barrier domains).
// Double-buffered K/V glds staging, 1 barrier/iter (unchanged).
// ============================================================================
__global__ __launch_bounds__(256, 2) void flash_k(const ushort_t* __restrict__ projf,
                                                  const ushort_t* __restrict__ gT,
                                                  float* __restrict__ opart,
                                                  float* __restrict__ oml,
                                                  int kqlog) {
    __shared__ __align__(16) ushort_t KsF[2][8192];  // fp16 K, frag-order, 16KB/buf
    __shared__ __align__(16) ushort_t VsF[2][8192];  // bf16 V, frag-order

    int b = blockIdx.y;
    int kq = blockIdx.x & ((1 << kqlog) - 1);
    int q0 = (blockIdx.x >> kqlog) * 128;
    int iters = 64 >> kqlog;
    int kt0 = kq * iters;
    int tid = threadIdx.x, w = tid >> 6, lane = tid & 63;
    int mrow = lane & 15, quad = lane >> 4, koff = quad * 8;

    // staging geometry: 4 chunks/thread/array; dest chunk-linear (frag order)
    int kRow[4], kCol[4], vIc[4], vOf[4], dstB[4];
    #pragma unroll
    for (int i = 0; i < 4; i++) {
        int c = w + i * 4;
        kRow[i] = (c >> 2) * 16 + mrow;
        kCol[i] = 128 + (c & 3) * 32 + koff;
        vIc[i]  = (c >> 1) * 16 + mrow;
        vOf[i]  = (c & 1) * 32 + koff;
        dstB[i] = c * 512;                           // shorts; wave-uniform base
    }

    // bpermute gather lanes (byte indices): src quad 2(t&1) (+1 for hi pair)
    int idx0 = (((quad & 1) << 5) + mrow) << 2;
    int idx1 = idx0 + 64;
    bool hiq = quad >= 2;                            // t>=2 -> odd-c (B) words

    half8 qf[2][4];                                  // 2 strips x 16 q-rows
    #pragma unroll
    for (int s = 0; s < 2; s++)
        #pragma unroll
        for (int kk = 0; kk < 4; kk++)
            qf[s][kk] = *(const half8*)(projf + (size_t)(b * 4096 + q0 + w * 32 + s * 16 + mrow) * 256
                                        + kk * 32 + koff);

    float4v oacc[2][8];
    float lsum[2] = {0.f, 0.f};
    #pragma unroll
    for (int s = 0; s < 2; s++)
        #pragma unroll
        for (int ot = 0; ot < 8; ot++) oacc[s][ot] = (float4v){0.f, 0.f, 0.f, 0.f};

    // prologue: stage kt0 into buf 0
    {
        int kb = kt0 * 64;
        #pragma unroll
        for (int i = 0; i < 4; i++) {
            glds16(projf + (size_t)(b * 4096 + kb + kRow[i]) * 256 + kCol[i], &KsF[0][dstB[i]]);
            glds16(gT + (size_t)(b * 128 + vIc[i]) * 4096 + kb + vOf[i], &VsF[0][dstB[i]]);
        }
    }

    for (int kt = kt0; kt < kt0 + iters; kt++) {
        int cur = (kt - kt0) & 1;
        __syncthreads();                             // publishes buf[cur] (vmcnt drain)
        if (kt + 1 < kt0 + iters) {                  // prefetch next into buf[1-cur]
            int kb = (kt + 1) * 64;
            #pragma unroll
            for (int i = 0; i < 4; i++) {
                glds16(projf + (size_t)(b * 4096 + kb + kRow[i]) * 256 + kCol[i], &KsF[1 - cur][dstB[i]]);
                glds16(gT + (size_t)(b * 128 + vIc[i]) * 4096 + kb + vOf[i], &VsF[1 - cur][dstB[i]]);
            }
        }

        // S^T = K.Q^T (fp16 in, f32 acc): D[key=quad*4+r (+16ct)][q=mrow]
        // then p=exp2(S-64)*... packed to bf16 pairs along key.
        unsigned int pk[2][4][2];
        #pragma unroll
        for (int ct = 0; ct < 4; ct++) {
            float4v a0 = {0.f, 0.f, 0.f, 0.f}, a1 = {0.f, 0.f, 0.f, 0.f};
            #pragma unroll
            for (int kk = 0; kk < 4; kk++) {
                half8 ah = *(const half8*)&KsF[cur][((ct * 4 + kk) * 64 + lane) * 8];
                a0 = __builtin_amdgcn_mfma_f32_16x16x32_f16(ah, qf[0][kk], a0, 0, 0, 0);
                a1 = __builtin_amdgcn_mfma_f32_16x16x32_f16(ah, qf[1][kk], a1, 0, 0, 0);
            }
            float p0[4], p1[4];
            #pragma unroll
            for (int r = 0; r < 4; r++) {
                p0[r] = __builtin_exp2f(fmaf(a0[r], 1.44269504f, -92.332481f));
                p1[r] = __builtin_exp2f(fmaf(a1[r], 1.44269504f, -92.332481f));
            }
            lsum[0] += (p0[0] + p0[1]) + (p0[2] + p0[3]);
            lsum[1] += (p1[0] + p1[1]) + (p1[2] + p1[3]);
            pk[0][ct][0] = pack2bf(p0[0], p0[1]);
            pk[0][ct][1] = pack2bf(p0[2], p0[3]);
            pk[1][ct][0] = pack2bf(p1[0], p1[1]);
            pk[1][ct][1] = pack2bf(p1[2], p1[3]);
        }

        // O += P.V ; A-frags built by in-register quad exchange
        #pragma unroll
        for (int k2 = 0; k2 < 2; k2++) {
            short8 af[2];
            #pragma unroll
            for (int s = 0; s < 2; s++) {
                int A0 = (int)pk[s][2 * k2][0],     A1 = (int)pk[s][2 * k2][1];
                int B0 = (int)pk[s][2 * k2 + 1][0], B1 = (int)pk[s][2 * k2 + 1][1];
                int gA0l = __builtin_amdgcn_ds_bpermute(idx0, A0);
                int gA1l = __builtin_amdgcn_ds_bpermute(idx0, A1);
                int gB0l = __builtin_amdgcn_ds_bpermute(idx0, B0);
                int gB1l = __builtin_amdgcn_ds_bpermute(idx0, B1);
                int gA0h = __builtin_amdgcn_ds_bpermute(idx1, A0);
                int gA1h = __builtin_amdgcn_ds_bpermute(idx1, A1);
                int gB0h = __builtin_amdgcn_ds_bpermute(idx1, B0);
                int gB1h = __builtin_amdgcn_ds_bpermute(idx1, B1);
                union { int u[4]; short8 s8; } fu;
                fu.u[0] = hiq ? gB0l : gA0l;
                fu.u[1] = hiq ? gB1l : gA1l;
                fu.u[2] = hiq ? gB0h : gA0h;
                fu.u[3] = hiq ? gB1h : gA1h;
                af[s] = fu.s8;
            }
            #pragma unroll
            for (int ot = 0; ot < 8; ot++) {
                short8 bfr = *(const short8*)&VsF[cur][((ot * 2 + k2) * 64 + lane) * 8];
                oacc[0][ot] = __builtin_amdgcn_mfma_f32_16x16x32_bf16(af[0], bfr, oacc[0][ot], 0, 0, 0);
                oacc[1][ot] = __builtin_amdgcn_mfma_f32_16x16x32_bf16(af[1], bfr, oacc[1][ot], 0, 0, 0);
            }
        }
    }

    // epilogue: raw partial O (common exp shift) + l
    #pragma unroll
    for (int s = 0; s < 2; s++)
        #pragma unroll
        for (int ot = 0; ot < 8; ot++)
            #pragma unroll
            for (int r = 0; r < 4; r++) {
                int R = b * 4096 + q0 + w * 32 + s * 16 + quad * 4 + r;
                opart[((size_t)kq * 16384 + R) * 128 + ot * 16 + mrow] = oacc[s][ot][r];
            }
    #pragma unroll
    for (int s = 0; s < 2; s++) {
        float l = lsum[s];
        l += __shfl_xor(l, 16, 64);
        l += __shfl_xor(l, 32, 64);                  // all quads summed
        if (lane < 16)                               // quad 0 writes, q = mrow
            oml[kq * 16384 + b * 4096 + q0 + w * 32 + s * 16 + lane] = l;
    }
}

// ============================================================================
// Kernel 4: wy = w_w . y2^T + w_b with inline merge of KQ partials
// (y2 = (sum O)/(sum l), common scale -> plain sums). 32-col n-tiles.
// ============================================================================
__global__ __launch_bounds__(256) void wy_k(const float* __restrict__ opart,
                                            const float* __restrict__ oml,
                                            const ushort_t* __restrict__ wwbh,
                                            const ushort_t* __restrict__ wwbl,
                                            const float* __restrict__ w_b,
                                            ushort_t* __restrict__ wy, int KQ) {
    int b = blockIdx.y, n0 = blockIdx.x * 32;
    int tid = threadIdx.x, w = tid >> 6, lane = tid & 63;
    int mrow = lane & 15, quad = lane >> 4, koff = quad * 8;
    int half = w & 1, sect = w >> 1;
    int Rn = b * 4096 + n0 + half * 16 + mrow;

    float L = 0.f;
    for (int kq = 0; kq < KQ; kq++) L += oml[kq * 16384 + Rn];
    float invL = 1.f / L;

    short8 bfh[4], bfl[4];
    #pragma unroll
    for (int kk = 0; kk < 4; kk++) {
        float a[8];
        #pragma unroll
        for (int j = 0; j < 8; j++) a[j] = 0.f;
        for (int kq = 0; kq < KQ; kq++) {
            const float* p = opart + ((size_t)kq * 16384 + Rn) * 128 + kk * 32 + koff;
            float4v v0 = *(const float4v*)p;
            float4v v1 = *(const float4v*)(p + 4);
            #pragma unroll
            for (int j = 0; j < 4; j++) { a[j] += v0[j]; a[4 + j] += v1[j]; }
        }
        #pragma unroll
        for (int j = 0; j < 8; j++) {
            ushort_t h, l;
            split2(a[j] * invL, h, l);
            bfh[kk][j] = (short)h; bfl[kk][j] = (short)l;
        }
    }

    int coln = n0 + half * 16 + mrow;
    for (int cot = sect * 8; cot < sect * 8 + 8; cot++) {
        float4v acc = {0.f, 0.f, 0.f, 0.f};
        #pragma unroll
        for (int kk = 0; kk < 4; kk++) {
            size_t woff = (size_t)(cot * 16 + mrow) * 128 + kk * 32 + koff;
            short8 ah = *(const short8*)(wwbh + woff);
            short8 al = *(const short8*)(wwbl + woff);
            acc = __builtin_amdgcn_mfma_f32_16x16x32_bf16(ah, bfh[kk], acc, 0, 0, 0);
            acc = __builtin_amdgcn_mfma_f32_16x16x32_bf16(ah, bfl[kk], acc, 0, 0, 0);
            acc = __builtin_amdgcn_mfma_f32_16x16x32_bf16(al, bfh[kk], acc, 0, 0, 0);
        }
        #pragma unroll
        for (int r = 0; r < 4; r++) {
            int co = cot * 16 + quad * 4 + r;
            wy[(size_t)(b * 256 + co) * 4096 + coln] = f2b(acc[r] + w_b[co]);
        }
    }
}

// ============================================================================
// Kernel 4b: per-channel sum/sumsq over wy. One block per channel.
// ============================================================================
__global__ __launch_bounds__(256) void stats_k(const ushort_t* __restrict__ wy,
                                               float* __restrict__ stats) {
    __shared__ float red[8];
    int co = blockIdx.x, tid = threadIdx.x, w = tid >> 6, lane = tid & 63;
    float s = 0.f, s2 = 0.f;
    #pragma unroll
    for (int i = 0; i < 8; i++) {
        int ch = tid + i * 256;
        int b = ch >> 9, n = (ch & 511) * 8;
        ushort8 v = *(const ushort8*)(wy + (size_t)(b * 256 + co) * 4096 + n);
        #pragma unroll
        for (int j = 0; j < 8; j++) { float f = b2f(v[j]); s += f; s2 += f * f; }
    }
    #pragma unroll
    for (int d = 1; d < 64; d <<= 1) { s += __shfl_xor(s, d, 64); s2 += __shfl_xor(s2, d, 64); }
    if (lane == 0) { red[w] = s; red[4 + w] = s2; }
    __syncthreads();
    if (tid == 0) {
        stats[co]       = red[0] + red[1] + red[2] + red[3];
        stats[256 + co] = red[4] + red[5] + red[6] + red[7];
    }
}

// ============================================================================
// Kernel 5: BN (batch stats, biased var, eps=1e-5) + residual, f32 out.
// ============================================================================
__global__ __launch_bounds__(256) void bn_k(const ushort_t* __restrict__ wy,
                                            const float* __restrict__ x,
                                            const float* __restrict__ gamma,
                                            const float* __restrict__ beta,
                                            const float* __restrict__ stats,
                                            float* __restrict__ out) {
    int idx = (blockIdx.x * 256 + threadIdx.x) * 8;     // B*C*N = 1<<22
    int c = (idx >> 12) & 255;
    const float inv_cnt = 1.f / 16384.f;
    float mean = stats[c] * inv_cnt;
    float var  = stats[256 + c] * inv_cnt - mean * mean;
    float inv  = rsqrtf(var + 1e-5f);
    float scale = gamma[c] * inv;
    float shift = beta[c] - mean * scale;
    ushort8 wv = *(const ushort8*)(wy + idx);
    float4v x0 = *(const float4v*)(x + idx);
    float4v x1 = *(const float4v*)(x + idx + 4);
    float4v o0, o1;
    #pragma unroll
    for (int j = 0; j < 4; j++) {
        o0[j] = b2f(wv[j]) * scale + shift + x0[j];
        o1[j] = b2f(wv[4 + j]) * scale + shift + x1[j];
    }
    *(float4v*)(out + idx) = o0;
    *(float4v*)(out + idx + 4) = o1;
}

extern "C" void kernel_launch(void* const* d_in, const int* in_sizes, int n_in,
                              void* d_out, int out_size, void* d_ws, size_t ws_size,
                              hipStream_t stream) {
    const float* x    = (const float*)d_in[0];
    const float* y    = (const float*)d_in[1];
    const float* g_w  = (const float*)d_in[2];
    const float* g_b  = (const float*)d_in[3];
    const float* dx_w = (const float*)d_in[4];
    const float* dx_b = (const float*)d_in[5];
    const float* dy_w = (const float*)d_in[6];
    const float* dy_b = (const float*)d_in[7];
    const float* w_w  = (const float*)d_in[8];
    const float* w_b  = (const float*)d_in[9];
    const float* bn_g = (const float*)d_in[10];
    const float* bn_b = (const float*)d_in[11];

    char* ws = (char*)d_ws;
    ushort_t* wtfh  = (ushort_t*)(ws + WTFH_OFF);
    ushort_t* wtfl  = (ushort_t*)(ws + WTFL_OFF);
    ushort_t* wwbh  = (ushort_t*)(ws + WWBH_OFF);
    ushort_t* wwbl  = (ushort_t*)(ws + WWBL_OFF);
    float*    bias  = (float*)(ws + BIAS_OFF);
    float*    stats = (float*)(ws + STATS_OFF);
    ushort_t* projf = (ushort_t*)(ws + PROJF_OFF);
    ushort_t* gT    = (ushort_t*)(ws + GT_OFF);
    float*    opart = (float*)(ws + OPART_OFF);
    ushort_t* wy    = (ushort_t*)(ws + WY_OFF);   // reuses projf region
    float*    out   = (float*)d_out;

    // ws-adaptive K-split: KQ=4 -> 512 blocks of 256 thr = 2 blocks/CU.
    int kqlog;
    if      (ws_size >= 13631488u + 4u * (8388608u + 65536u)) kqlog = 2;
    else if (ws_size >= 13631488u + 2u * (8388608u + 65536u)) kqlog = 1;
    else                                                      kqlog = 0;
    int KQ = 1 << kqlog;
    float* oml = (float*)(ws + OPART_OFF + (size_t)KQ * 8388608u);

    prep_k<<<384, 256, 0, stream>>>(dx_w, dy_w, g_w, dx_b, dy_b, g_b, w_w,
                                    wtfh, wtfl, wwbh, wwbl, bias);
    proj_k<<<dim3(128, 4), 256, 0, stream>>>(x, y, wtfh, wtfl, bias, projf, gT);
    flash_k<<<dim3(32 << kqlog, 4), 256, 0, stream>>>(projf, gT, opart, oml, kqlog);
    wy_k<<<dim3(128, 4), 256, 0, stream>>>(opart, oml, wwbh, wwbl, w_b, wy, KQ);
    stats_k<<<256, 256, 0, stream>>>(wy, stats);
    bn_k<<<2048, 256, 0, stream>>>(wy, x, bn_g, bn_b, stats, out);
}